// Round 8
// baseline (208.582 us; speedup 1.0000x reference)
//
#include <hip/hip_runtime.h>
#include <hip/hip_bf16.h>

// Shapes fixed by the problem instance.
#define BB   8
#define TT   256
#define NH   8
#define CC   16
#define HH   16
#define WW   32
#define LL   512
#define DCH  32
#define GC   8

// LDS image pair strides (ushorts). 1928*2 B => bank shift 4/pair, so quads
// 0/1 (pairs p and p+4) tile disjoint 16-bank sets: every A-read is 2-way.
// [measured r5/r7: SQ_LDS_BANK_CONFLICT == 0 with this layout]
#define PSC  1928   // k_cov: 960 pix + 4 pad slots
#define PSG  1736   // k_gate: 864 pix + 4 pad slots

typedef __attribute__((ext_vector_type(8))) short s8b;
typedef __attribute__((ext_vector_type(4))) float f32x4;

__device__ __forceinline__ ushort f2bfu(float v) {
  __hip_bfloat16 h = __float2bfloat16(v);
  ushort s;
  __builtin_memcpy(&s, &h, 2);
  return s;
}

// ---------------------------------------------------------------------------
// K0: pack weights into MFMA B-fragment layouts; zero BN sums.
__global__ __launch_bounds__(256) void k_gen(const float* __restrict__ cw,
                                             const float* __restrict__ pw,
                                             const float* __restrict__ gw1,
                                             ushort* __restrict__ bfrag,
                                             ushort* __restrict__ pwf,
                                             ushort* __restrict__ bfragG,
                                             float* __restrict__ sums) {
  int idx = blockIdx.x * 256 + threadIdx.x;
  if (idx < 17) sums[idx] = 0.f;
  if (idx < 13312) {
    int j = idx & 7, lane = (idx >> 3) & 63, nt = (idx >> 9) & 1, s = idx >> 10;
    int quad = lane >> 4, col = lane & 15;
    int k = s * 32 + quad * 8 + j;
    int n = nt * 16 + col;
    float v = (k < 400) ? cw[(n * CC + (k & 15)) * 25 + (k >> 4)] : 0.f;
    bfrag[idx] = f2bfu(v);
  } else if (idx < 13824) {
    int i2 = idx - 13312;
    int j = i2 & 7, lane = i2 >> 3;
    int quad = lane >> 4, col = lane & 15;
    float v = (col < NH) ? pw[col * DCH + quad * 8 + j] : 0.f;
    pwf[i2] = f2bfu(v);
  } else if (idx < 16384) {
    int i3 = idx - 13824;
    int j = i3 & 7, lane = (i3 >> 3) & 63, s = i3 >> 9;  // s<5
    int quad = lane >> 4, col = lane & 15;
    int k = s * 32 + quad * 8 + j;
    float v = 0.f;
    if (k < 144 && col < GC) v = gw1[(col * CC + (k & 15)) * 9 + (k >> 4)];
    bfragG[i3] = f2bfu(v);
  }
}

// ---------------------------------------------------------------------------
// K1: gate network via MFMA (3x3 conv 16->8 + pool + FC + sigmoid).
// Writes ONLY gate2[b][c][t]. One block = (b,t).
__global__ __launch_bounds__(256, 4) void k_gate(
    const float* __restrict__ prev, const float* __restrict__ curr,
    const ushort* __restrict__ bfragG, const float* __restrict__ gb1,
    const float* __restrict__ gw2, const float* __restrict__ gb2,
    float* __restrict__ gate2) {
  __shared__ __align__(16) ushort img[8 * PSG];
  __shared__ float redg[64];
  __shared__ float pooled[16];

  int tid = threadIdx.x;
  int lane = tid & 63, w = tid >> 6;
  int bt = blockIdx.x;
  int b = bt >> 8, t = bt & 255;
  int quad = lane >> 4, col = lane & 15;
  int qh = quad >> 1, icb = (quad & 1) * 8;

  // zero image: 8*PSG ushorts = PSG uint4
  for (int i = tid; i < PSG; i += 256) ((uint4*)img)[i] = (uint4){0, 0, 0, 0};
  __syncthreads();

  // stage: pair-interleaved fill, contiguous b64 writes
#pragma unroll
  for (int it = 0; it < 4; ++it) {
#pragma unroll
    for (int e = 0; e < 2; ++e) {
      int W = ((it * 4 + w) * 2 + e) * 64 + lane;  // 0..2047
      int cp = W >> 8, pp = W & 255;
      int l0 = pp * 2;
      const float* src = (cp < 4) ? prev : curr;
      int chb = (cp & 3) * 2;
      const float* p0 = src + ((size_t)(b * NH + chb) * TT + t) * LL + l0;
      float2 fa = *(const float2*)p0;
      float2 fb = *(const float2*)(p0 + TT * LL);
      unsigned lo = (unsigned)f2bfu(fa.x) | ((unsigned)f2bfu(fb.x) << 16);
      unsigned hi = (unsigned)f2bfu(fa.y) | ((unsigned)f2bfu(fb.y) << 16);
      int r = l0 >> 5, x = l0 & 31;
      int slot = (r + 1) * 48 + 8 + x;
      *(uint2*)&img[cp * PSG + slot * 2] = (uint2){lo, hi};
    }
  }
  __syncthreads();

  // K-loop: 5 steps of K=32 (2 taps x 16 ic)
  f32x4 acc[8];
#pragma unroll
  for (int mi = 0; mi < 8; ++mi) acc[mi] = (f32x4){0.f, 0.f, 0.f, 0.f};
  int mtbase = w * 8;
  int ab[8];
#pragma unroll
  for (int mi = 0; mi < 8; ++mi) {
    int mt = mtbase + mi;
    int py = mt >> 1, px = ((mt & 1) << 4) + col;
    ab[mi] = (icb >> 1) * PSG + (py * 48 + 7 + px) * 2;
  }
  const int offE[5] = {0, 2, 49, 96, 98};
  const int offO[5] = {1, 48, 50, 97, 98};  // last = dummy (B zero)
  const s8b* bG = (const s8b*)bfragG;
#pragma unroll
  for (int s = 0; s < 5; ++s) {
    s8b bf = bG[s * 64 + lane];
    int off2 = (qh ? offO[s] : offE[s]) * 2;
#pragma unroll
    for (int mi = 0; mi < 8; ++mi) {
      union { unsigned u[4]; s8b v; } A;
      int a0 = ab[mi] + off2;
#pragma unroll
      for (int p = 0; p < 4; ++p) A.u[p] = *(const unsigned*)&img[a0 + p * PSG];
      acc[mi] = __builtin_amdgcn_mfma_f32_16x16x32_bf16(A.v, bf, acc[mi], 0, 0, 0);
    }
  }

  // pool: mean over 512 pixels of relu(conv + b1), per oc (=col)
  float gb1c = (col < GC) ? gb1[col] : 0.f;
  float s = 0.f;
#pragma unroll
  for (int mi = 0; mi < 8; ++mi)
#pragma unroll
    for (int r = 0; r < 4; ++r) s += fmaxf(acc[mi][r] + gb1c, 0.f);
  s += __shfl_down(s, 16, 64);
  s += __shfl_down(s, 32, 64);
  if (lane < 16) redg[w * 16 + lane] = s;
  __syncthreads();
  if (tid < 16)
    pooled[tid] = (redg[tid] + redg[16 + tid] + redg[32 + tid] + redg[48 + tid]) *
                  (1.0f / (float)LL);
  __syncthreads();
  if (tid < 16) {
    float z = gb2[tid];
#pragma unroll
    for (int i = 0; i < GC; ++i) z = fmaf(pooled[i], gw2[tid * GC + i], z);
    gate2[(b * CC + tid) * TT + t] = 1.f / (1.f + __expf(-z));
  }
}

// ---------------------------------------------------------------------------
// K2: single-kernel chunked exclusive cumsum of attn*gate, bf16 out.
// Block = (b, c, 64-wide l-group); thread (tc in [0,4), li in [0,64)).
// Phase 1: each thread sums its 64-t chunk (coalesced 256 B wave loads,
// gate wave-uniform). LDS fixup gives the chunk prefix; phase 2 re-reads
// (L2-hot, 64 KB/block) and writes the exclusive scan. 4x the waves of the
// single-pass scan, serial chain 128 instead of 256.
__global__ __launch_bounds__(256) void k_cum(const float* __restrict__ prev,
                                             const float* __restrict__ curr,
                                             const float* __restrict__ gate2,
                                             ushort* __restrict__ cum) {
  __shared__ float cs[256];
  int bid = blockIdx.x;            // 1024 blocks
  int lg = bid & 7;
  int c = (bid >> 3) & 15;
  int b = bid >> 7;
  int tid = threadIdx.x;
  int li = tid & 63, tc = tid >> 6;   // tc uniform per wave

  const float* src = (c < NH) ? prev : curr;
  const float* a = src + ((size_t)(b * NH + (c & 7)) * TT + tc * 64) * LL + lg * 64 + li;
  const float* g = gate2 + (b * CC + c) * TT + tc * 64;

  float s = 0.f;
#pragma unroll 8
  for (int j = 0; j < 64; ++j) s = fmaf(a[(size_t)j * LL], g[j], s);
  cs[tc * 64 + li] = s;
  __syncthreads();

  float run = 0.f;
  for (int u = 0; u < tc; ++u) run += cs[u * 64 + li];  // wave-uniform count

  ushort* o = cum + ((size_t)(b * CC + c) * TT + tc * 64) * LL + lg * 64 + li;
#pragma unroll 8
  for (int j = 0; j < 64; ++j) {
    o[(size_t)j * LL] = f2bfu(run);  // exclusive
    run = fmaf(a[(size_t)j * LL], g[j], run);
  }
}

// ---------------------------------------------------------------------------
// K3: MFMA implicit-GEMM 5x5 conv 16->32 (+bias+relu), mask, 1x1 proj MFMA,
// BN-sum accumulation. One block = one (b,t) image.  [round-5 structure;
// launch_bounds 2->4 blocks/CU: LDS 36.9KB*4=147KB<=160, VGPR 60<=128]
__global__ __launch_bounds__(256, 4) void k_cov(
    const ushort* __restrict__ cum, const ushort* __restrict__ bfrag,
    const ushort* __restrict__ pwf, const float* __restrict__ cb,
    const int* __restrict__ mask, float* __restrict__ out,
    float* __restrict__ sums) {
  __shared__ __align__(16) ushort img[8 * PSC];
  __shared__ __align__(16) ushort scr[4 * 640];   // per wave 32 oc * 20
  __shared__ float redp[128];
  __shared__ float redc[4];

  int tid = threadIdx.x;
  int lane = tid & 63, w = tid >> 6;
  int bt = blockIdx.x;
  int b = bt >> 8, t = bt & 255;
  int quad = lane >> 4, col = lane & 15;
  int qh = quad >> 1, icb = (quad & 1) * 8;

  // zero image: 8*PSC ushorts = PSC uint4
  for (int i = tid; i < PSC; i += 256) ((uint4*)img)[i] = (uint4){0, 0, 0, 0};
  __syncthreads();

  // stage (bf16 pair-interleave, contiguous b64 writes)
#pragma unroll
  for (int it = 0; it < 4; ++it) {
#pragma unroll
    for (int e = 0; e < 2; ++e) {
      int W = ((it * 4 + w) * 2 + e) * 64 + lane;  // 0..2047
      int cp = W >> 8, pp = W & 255;
      int l0 = pp * 2;
      const ushort* p0 = cum + ((size_t)(b * CC + cp * 2) * TT + t) * LL + l0;
      unsigned a = *(const unsigned*)p0;
      unsigned bb2 = *(const unsigned*)(p0 + TT * LL);
      unsigned lo = (a & 0xFFFFu) | (bb2 << 16);
      unsigned hi = (a >> 16) | (bb2 & 0xFFFF0000u);
      int r = l0 >> 5, x = l0 & 31;
      int slot = (r + 2) * 48 + 8 + x;
      *(uint2*)&img[cp * PSC + slot * 2] = (uint2){lo, hi};
    }
  }
  __syncthreads();

  // K-loop: 13 steps of K=32 (2 taps x 16 ic)
  f32x4 acc[8][2];
#pragma unroll
  for (int mi = 0; mi < 8; ++mi) {
    acc[mi][0] = (f32x4){0.f, 0.f, 0.f, 0.f};
    acc[mi][1] = (f32x4){0.f, 0.f, 0.f, 0.f};
  }
  int mtbase = w * 8;
  int ab[8];
#pragma unroll
  for (int mi = 0; mi < 8; ++mi) {
    int mt = mtbase + mi;
    int py = mt >> 1, px = ((mt & 1) << 4) + col;
    ab[mi] = (icb >> 1) * PSC + (py * 48 + 6 + px) * 2;
  }
  const int offE[13] = {0, 2, 4, 49, 51, 96, 98, 100, 145, 147, 192, 194, 196};
  const int offO[13] = {1, 3, 48, 50, 52, 97, 99, 144, 146, 148, 193, 195, 196};
  const s8b* bfr = (const s8b*)bfrag;
#pragma unroll
  for (int s = 0; s < 13; ++s) {
    s8b bf0 = bfr[(s * 2) * 64 + lane];
    s8b bf1 = bfr[(s * 2 + 1) * 64 + lane];
    int off2 = (qh ? offO[s] : offE[s]) * 2;
#pragma unroll
    for (int mi = 0; mi < 8; ++mi) {
      union { unsigned u[4]; s8b v; } A;
      int a0 = ab[mi] + off2;
#pragma unroll
      for (int p = 0; p < 4; ++p) A.u[p] = *(const unsigned*)&img[a0 + p * PSC];
      acc[mi][0] = __builtin_amdgcn_mfma_f32_16x16x32_bf16(A.v, bf0, acc[mi][0], 0, 0, 0);
      acc[mi][1] = __builtin_amdgcn_mfma_f32_16x16x32_bf16(A.v, bf1, acc[mi][1], 0, 0, 0);
    }
  }

  // epilogue: wave-private scr round-trip (C-layout -> A-layout), proj MFMA,
  // mask, store, BN partials. scr row = oc (stride 20), cols = 16 pixels.
  int wb = w * 640;
  float cb0 = cb[col], cb1 = cb[col + 16];
  s8b pf = ((const s8b*)pwf)[lane];
  float psum = 0.f, psq = 0.f, pcnt = 0.f;
  float* outbase = out + ((size_t)(b * NH + col) * TT + t) * LL;  // col<8 only
  const int* mrow = mask + b * LL;
#pragma unroll
  for (int mi = 0; mi < 8; ++mi) {
    int mt = mtbase + mi;
    ushort w0[4], w1[4];
#pragma unroll
    for (int r = 0; r < 4; ++r) {
      w0[r] = f2bfu(fmaxf(acc[mi][0][r] + cb0, 0.f));
      w1[r] = f2bfu(fmaxf(acc[mi][1][r] + cb1, 0.f));
    }
    uint2 pk0, pk1;
    __builtin_memcpy(&pk0, w0, 8);
    __builtin_memcpy(&pk1, w1, 8);
    *(uint2*)&scr[wb + col * 20 + quad * 4] = pk0;          // oc=col
    *(uint2*)&scr[wb + (col + 16) * 20 + quad * 4] = pk1;   // oc=col+16
    ushort u[8];
#pragma unroll
    for (int e = 0; e < 8; ++e) u[e] = scr[wb + (quad * 8 + e) * 20 + col];
    s8b a2;
    __builtin_memcpy(&a2, u, 16);
    f32x4 zero = {0.f, 0.f, 0.f, 0.f};
    f32x4 d2 = __builtin_amdgcn_mfma_f32_16x16x32_bf16(a2, pf, zero, 0, 0, 0);
    int4 m4 = *(const int4*)(mrow + mt * 16 + quad * 4);
    float k0 = m4.x ? 0.f : 1.f;
    float k1 = m4.y ? 0.f : 1.f;
    float k2 = m4.z ? 0.f : 1.f;
    float k3 = m4.w ? 0.f : 1.f;
    if (col < NH) {
      float* op = outbase + mt * 16 + quad * 4;
      float v0 = d2[0] * k0; op[0] = v0; psum += v0; psq += v0 * v0;
      float v1 = d2[1] * k1; op[1] = v1; psum += v1; psq += v1 * v1;
      float v2 = d2[2] * k2; op[2] = v2; psum += v2; psq += v2 * v2;
      float v3 = d2[3] * k3; op[3] = v3; psum += v3; psq += v3 * v3;
    }
    if (col == 0) pcnt += k0 + k1 + k2 + k3;
  }

  psum += __shfl_down(psum, 16, 64); psum += __shfl_down(psum, 32, 64);
  psq  += __shfl_down(psq, 16, 64);  psq  += __shfl_down(psq, 32, 64);
  pcnt += __shfl_down(pcnt, 16, 64); pcnt += __shfl_down(pcnt, 32, 64);
  if (lane < 16) {
    redp[(w * 16 + lane) * 2] = psum;
    redp[(w * 16 + lane) * 2 + 1] = psq;
    if (lane == 0) redc[w] = pcnt;
  }
  __syncthreads();
  if (tid < 17) {
    float v;
    if (tid < 8) {
      v = redp[tid * 2] + redp[(16 + tid) * 2] + redp[(32 + tid) * 2] + redp[(48 + tid) * 2];
    } else if (tid < 16) {
      int nh = tid - 8;
      v = redp[nh * 2 + 1] + redp[(16 + nh) * 2 + 1] + redp[(32 + nh) * 2 + 1] + redp[(48 + nh) * 2 + 1];
    } else {
      v = redc[0] + redc[1] + redc[2] + redc[3];
    }
    atomicAdd(&sums[tid], v);
  }
}

// ---------------------------------------------------------------------------
// K4: masked BN normalize in-place.
__global__ __launch_bounds__(256) void k_bn(
    float* __restrict__ out, const float* __restrict__ sums,
    const int* __restrict__ mask, const float* __restrict__ gamma,
    const float* __restrict__ beta) {
  __shared__ float sc[NH], sh[NH];
  int tid = threadIdx.x;
  if (tid < NH) {
    float cnt = sums[16];
    float mean = sums[tid] / cnt;
    float var = sums[NH + tid] / cnt - mean * mean;
    float inv = rsqrtf(var + 1e-5f) * gamma[tid];
    sc[tid] = inv;
    sh[tid] = fmaf(-mean, inv, beta[tid]);
  }
  __syncthreads();
  size_t e = ((size_t)blockIdx.x * 256 + tid) * 4;
  int l = (int)(e & (LL - 1));
  int bn = (int)(e >> 17);
  int n = bn & 7, b = bn >> 3;
  const int4 mv = *(const int4*)(mask + b * LL + l);
  float4 v = *(float4*)(out + e);
  float s = sc[n], h = sh[n];
  v.x = mv.x ? v.x : fmaf(v.x, s, h);
  v.y = mv.y ? v.y : fmaf(v.y, s, h);
  v.z = mv.z ? v.z : fmaf(v.z, s, h);
  v.w = mv.w ? v.w : fmaf(v.w, s, h);
  *(float4*)(out + e) = v;
}

// ---------------------------------------------------------------------------
extern "C" void kernel_launch(void* const* d_in, const int* in_sizes, int n_in,
                              void* d_out, int out_size, void* d_ws, size_t ws_size,
                              hipStream_t stream) {
  const float* prev   = (const float*)d_in[0];
  const int*   mask   = (const int*)d_in[1];
  const float* curr   = (const float*)d_in[3];
  const float* conv_w = (const float*)d_in[5];
  const float* conv_b = (const float*)d_in[6];
  const float* proj_w = (const float*)d_in[7];
  const float* g_w1   = (const float*)d_in[8];
  const float* g_b1   = (const float*)d_in[9];
  const float* g_w2   = (const float*)d_in[10];
  const float* g_b2   = (const float*)d_in[11];
  const float* bn_g   = (const float*)d_in[12];
  const float* bn_b   = (const float*)d_in[13];
  float* out = (float*)d_out;

  char* ws = (char*)d_ws;
  ushort* bfrag  = (ushort*)(ws);                    // 26624 B
  ushort* pwf    = (ushort*)(ws + 26624);            // 1024 B
  ushort* bfragG = (ushort*)(ws + 27648);            // 5120 B
  float*  sums   = (float*)(ws + 32768);             // 68 B
  float*  gate2  = (float*)(ws + 36864);             // 131072 B  [b][c][t]
  ushort* cum    = (ushort*)(ws + 36864 + 131072);   // 33554432 B [b][c][t][l]

  k_gen<<<64, 256, 0, stream>>>(conv_w, proj_w, g_w1, bfrag, pwf, bfragG, sums);
  k_gate<<<BB * TT, 256, 0, stream>>>(prev, curr, bfragG, g_b1, g_w2, g_b2, gate2);
  k_cum<<<BB * CC * 8, 256, 0, stream>>>(prev, curr, gate2, cum);
  k_cov<<<BB * TT, 256, 0, stream>>>(cum, bfrag, pwf, conv_b, mask, out, sums);
  k_bn<<<(BB * NH * TT * LL) / (256 * 4), 256, 0, stream>>>(out, sums, mask, bn_g, bn_b);
}

// Round 9
// 200.653 us; speedup vs baseline: 1.0395x; 1.0395x over previous
//
#include <hip/hip_runtime.h>
#include <hip/hip_bf16.h>

// Shapes fixed by the problem instance.
#define BB   8
#define TT   256
#define NH   8
#define CC   16
#define HH   16
#define WW   32
#define LL   512
#define DCH  32
#define GC   8

// LDS image pair strides (ushorts). 1928*2 B => bank shift 4/pair, so quads
// 0/1 (pairs p and p+4) tile disjoint 16-bank sets: every A-read is 2-way.
// [measured r5/r7/r8: SQ_LDS_BANK_CONFLICT == 0 with this layout]
#define PSC  1928   // k_cov: 960 pix + 4 pad slots
#define PSG  1736   // k_gate: 864 pix + 4 pad slots

typedef __attribute__((ext_vector_type(8))) short s8b;
typedef __attribute__((ext_vector_type(4))) float f32x4;

__device__ __forceinline__ ushort f2bfu(float v) {
  __hip_bfloat16 h = __float2bfloat16(v);
  ushort s;
  __builtin_memcpy(&s, &h, 2);
  return s;
}

// ---------------------------------------------------------------------------
// K0: pack weights into MFMA B-fragment layouts; zero BN sums.
__global__ __launch_bounds__(256) void k_gen(const float* __restrict__ cw,
                                             const float* __restrict__ pw,
                                             const float* __restrict__ gw1,
                                             ushort* __restrict__ bfrag,
                                             ushort* __restrict__ pwf,
                                             ushort* __restrict__ bfragG,
                                             float* __restrict__ sums) {
  int idx = blockIdx.x * 256 + threadIdx.x;
  if (idx < 17) sums[idx] = 0.f;
  if (idx < 13312) {
    int j = idx & 7, lane = (idx >> 3) & 63, nt = (idx >> 9) & 1, s = idx >> 10;
    int quad = lane >> 4, col = lane & 15;
    int k = s * 32 + quad * 8 + j;
    int n = nt * 16 + col;
    float v = (k < 400) ? cw[(n * CC + (k & 15)) * 25 + (k >> 4)] : 0.f;
    bfrag[idx] = f2bfu(v);
  } else if (idx < 13824) {
    int i2 = idx - 13312;
    int j = i2 & 7, lane = i2 >> 3;
    int quad = lane >> 4, col = lane & 15;
    float v = (col < NH) ? pw[col * DCH + quad * 8 + j] : 0.f;
    pwf[i2] = f2bfu(v);
  } else if (idx < 16384) {
    int i3 = idx - 13824;
    int j = i3 & 7, lane = (i3 >> 3) & 63, s = i3 >> 9;  // s<5
    int quad = lane >> 4, col = lane & 15;
    int k = s * 32 + quad * 8 + j;
    float v = 0.f;
    if (k < 144 && col < GC) v = gw1[(col * CC + (k & 15)) * 9 + (k >> 4)];
    bfragG[i3] = f2bfu(v);
  }
}

// ---------------------------------------------------------------------------
// K1: gate network via MFMA (3x3 conv 16->8 + pool + FC + sigmoid).
// Writes ONLY gate2[b][c][t]. One block = (b,t).
__global__ __launch_bounds__(256, 4) void k_gate(
    const float* __restrict__ prev, const float* __restrict__ curr,
    const ushort* __restrict__ bfragG, const float* __restrict__ gb1,
    const float* __restrict__ gw2, const float* __restrict__ gb2,
    float* __restrict__ gate2) {
  __shared__ __align__(16) ushort img[8 * PSG];
  __shared__ float redg[64];
  __shared__ float pooled[16];

  int tid = threadIdx.x;
  int lane = tid & 63, w = tid >> 6;
  int bt = blockIdx.x;
  int b = bt >> 8, t = bt & 255;
  int quad = lane >> 4, col = lane & 15;
  int qh = quad >> 1, icb = (quad & 1) * 8;

  // zero image: 8*PSG ushorts = PSG uint4
  for (int i = tid; i < PSG; i += 256) ((uint4*)img)[i] = (uint4){0, 0, 0, 0};
  __syncthreads();

  // stage: pair-interleaved fill, contiguous b64 writes
#pragma unroll
  for (int it = 0; it < 4; ++it) {
#pragma unroll
    for (int e = 0; e < 2; ++e) {
      int W = ((it * 4 + w) * 2 + e) * 64 + lane;  // 0..2047
      int cp = W >> 8, pp = W & 255;
      int l0 = pp * 2;
      const float* src = (cp < 4) ? prev : curr;
      int chb = (cp & 3) * 2;
      const float* p0 = src + ((size_t)(b * NH + chb) * TT + t) * LL + l0;
      float2 fa = *(const float2*)p0;
      float2 fb = *(const float2*)(p0 + TT * LL);
      unsigned lo = (unsigned)f2bfu(fa.x) | ((unsigned)f2bfu(fb.x) << 16);
      unsigned hi = (unsigned)f2bfu(fa.y) | ((unsigned)f2bfu(fb.y) << 16);
      int r = l0 >> 5, x = l0 & 31;
      int slot = (r + 1) * 48 + 8 + x;
      *(uint2*)&img[cp * PSG + slot * 2] = (uint2){lo, hi};
    }
  }
  __syncthreads();

  // K-loop: 5 steps of K=32 (2 taps x 16 ic)
  f32x4 acc[8];
#pragma unroll
  for (int mi = 0; mi < 8; ++mi) acc[mi] = (f32x4){0.f, 0.f, 0.f, 0.f};
  int mtbase = w * 8;
  int ab[8];
#pragma unroll
  for (int mi = 0; mi < 8; ++mi) {
    int mt = mtbase + mi;
    int py = mt >> 1, px = ((mt & 1) << 4) + col;
    ab[mi] = (icb >> 1) * PSG + (py * 48 + 7 + px) * 2;
  }
  const int offE[5] = {0, 2, 49, 96, 98};
  const int offO[5] = {1, 48, 50, 97, 98};  // last = dummy (B zero)
  const s8b* bG = (const s8b*)bfragG;
#pragma unroll
  for (int s = 0; s < 5; ++s) {
    s8b bf = bG[s * 64 + lane];
    int off2 = (qh ? offO[s] : offE[s]) * 2;
#pragma unroll
    for (int mi = 0; mi < 8; ++mi) {
      union { unsigned u[4]; s8b v; } A;
      int a0 = ab[mi] + off2;
#pragma unroll
      for (int p = 0; p < 4; ++p) A.u[p] = *(const unsigned*)&img[a0 + p * PSG];
      acc[mi] = __builtin_amdgcn_mfma_f32_16x16x32_bf16(A.v, bf, acc[mi], 0, 0, 0);
    }
  }

  // pool: mean over 512 pixels of relu(conv + b1), per oc (=col)
  float gb1c = (col < GC) ? gb1[col] : 0.f;
  float s = 0.f;
#pragma unroll
  for (int mi = 0; mi < 8; ++mi)
#pragma unroll
    for (int r = 0; r < 4; ++r) s += fmaxf(acc[mi][r] + gb1c, 0.f);
  s += __shfl_down(s, 16, 64);
  s += __shfl_down(s, 32, 64);
  if (lane < 16) redg[w * 16 + lane] = s;
  __syncthreads();
  if (tid < 16)
    pooled[tid] = (redg[tid] + redg[16 + tid] + redg[32 + tid] + redg[48 + tid]) *
                  (1.0f / (float)LL);
  __syncthreads();
  if (tid < 16) {
    float z = gb2[tid];
#pragma unroll
    for (int i = 0; i < GC; ++i) z = fmaf(pooled[i], gw2[tid * GC + i], z);
    gate2[(b * CC + tid) * TT + t] = 1.f / (1.f + __expf(-z));
  }
}

// ---------------------------------------------------------------------------
// K2: single-pass exclusive cumsum over t of attn*gate, bf16 out.
// One thread per (b,c,l) column; gate load is wave-uniform.
// unroll 16: 16 independent 256 B/wave loads in flight -> covers L3-hit
// latency (attn is L3-warm from k_gate's read).
__global__ __launch_bounds__(256) void k_cum(const float* __restrict__ prev,
                                             const float* __restrict__ curr,
                                             const float* __restrict__ gate2,
                                             ushort* __restrict__ cum) {
  int idx = blockIdx.x * 256 + threadIdx.x;
  int l = idx & 511;
  int c = (idx >> 9) & 15;
  int b = idx >> 13;
  const float* src = (c < NH) ? prev : curr;
  const float* a = src + (size_t)(b * NH + (c & 7)) * TT * LL + l;
  const float* g = gate2 + (b * CC + c) * TT;
  ushort* o = cum + (size_t)(b * CC + c) * TT * LL + l;
  float run = 0.f;
#pragma unroll 16
  for (int t = 0; t < TT; ++t) {
    float av = a[(size_t)t * LL];
    float gv = g[t];
    o[(size_t)t * LL] = f2bfu(run);  // exclusive
    run = fmaf(av, gv, run);
  }
}

// ---------------------------------------------------------------------------
// K3: MFMA implicit-GEMM 5x5 conv 16->32 (+bias+relu), mask, 1x1 proj MFMA,
// BN-sum accumulation. One block = one (b,t) image.  [r8-verbatim: 49.9 us,
// 0 conflicts, (256,4) verified win]
__global__ __launch_bounds__(256, 4) void k_cov(
    const ushort* __restrict__ cum, const ushort* __restrict__ bfrag,
    const ushort* __restrict__ pwf, const float* __restrict__ cb,
    const int* __restrict__ mask, float* __restrict__ out,
    float* __restrict__ sums) {
  __shared__ __align__(16) ushort img[8 * PSC];
  __shared__ __align__(16) ushort scr[4 * 640];   // per wave 32 oc * 20
  __shared__ float redp[128];
  __shared__ float redc[4];

  int tid = threadIdx.x;
  int lane = tid & 63, w = tid >> 6;
  int bt = blockIdx.x;
  int b = bt >> 8, t = bt & 255;
  int quad = lane >> 4, col = lane & 15;
  int qh = quad >> 1, icb = (quad & 1) * 8;

  // zero image: 8*PSC ushorts = PSC uint4
  for (int i = tid; i < PSC; i += 256) ((uint4*)img)[i] = (uint4){0, 0, 0, 0};
  __syncthreads();

  // stage (bf16 pair-interleave, contiguous b64 writes)
#pragma unroll
  for (int it = 0; it < 4; ++it) {
#pragma unroll
    for (int e = 0; e < 2; ++e) {
      int W = ((it * 4 + w) * 2 + e) * 64 + lane;  // 0..2047
      int cp = W >> 8, pp = W & 255;
      int l0 = pp * 2;
      const ushort* p0 = cum + ((size_t)(b * CC + cp * 2) * TT + t) * LL + l0;
      unsigned a = *(const unsigned*)p0;
      unsigned bb2 = *(const unsigned*)(p0 + TT * LL);
      unsigned lo = (a & 0xFFFFu) | (bb2 << 16);
      unsigned hi = (a >> 16) | (bb2 & 0xFFFF0000u);
      int r = l0 >> 5, x = l0 & 31;
      int slot = (r + 2) * 48 + 8 + x;
      *(uint2*)&img[cp * PSC + slot * 2] = (uint2){lo, hi};
    }
  }
  __syncthreads();

  // K-loop: 13 steps of K=32 (2 taps x 16 ic)
  f32x4 acc[8][2];
#pragma unroll
  for (int mi = 0; mi < 8; ++mi) {
    acc[mi][0] = (f32x4){0.f, 0.f, 0.f, 0.f};
    acc[mi][1] = (f32x4){0.f, 0.f, 0.f, 0.f};
  }
  int mtbase = w * 8;
  int ab[8];
#pragma unroll
  for (int mi = 0; mi < 8; ++mi) {
    int mt = mtbase + mi;
    int py = mt >> 1, px = ((mt & 1) << 4) + col;
    ab[mi] = (icb >> 1) * PSC + (py * 48 + 6 + px) * 2;
  }
  const int offE[13] = {0, 2, 4, 49, 51, 96, 98, 100, 145, 147, 192, 194, 196};
  const int offO[13] = {1, 3, 48, 50, 52, 97, 99, 144, 146, 148, 193, 195, 196};
  const s8b* bfr = (const s8b*)bfrag;
#pragma unroll
  for (int s = 0; s < 13; ++s) {
    s8b bf0 = bfr[(s * 2) * 64 + lane];
    s8b bf1 = bfr[(s * 2 + 1) * 64 + lane];
    int off2 = (qh ? offO[s] : offE[s]) * 2;
#pragma unroll
    for (int mi = 0; mi < 8; ++mi) {
      union { unsigned u[4]; s8b v; } A;
      int a0 = ab[mi] + off2;
#pragma unroll
      for (int p = 0; p < 4; ++p) A.u[p] = *(const unsigned*)&img[a0 + p * PSC];
      acc[mi][0] = __builtin_amdgcn_mfma_f32_16x16x32_bf16(A.v, bf0, acc[mi][0], 0, 0, 0);
      acc[mi][1] = __builtin_amdgcn_mfma_f32_16x16x32_bf16(A.v, bf1, acc[mi][1], 0, 0, 0);
    }
  }

  // epilogue: wave-private scr round-trip (C-layout -> A-layout), proj MFMA,
  // mask, store, BN partials. scr row = oc (stride 20), cols = 16 pixels.
  int wb = w * 640;
  float cb0 = cb[col], cb1 = cb[col + 16];
  s8b pf = ((const s8b*)pwf)[lane];
  float psum = 0.f, psq = 0.f, pcnt = 0.f;
  float* outbase = out + ((size_t)(b * NH + col) * TT + t) * LL;  // col<8 only
  const int* mrow = mask + b * LL;
#pragma unroll
  for (int mi = 0; mi < 8; ++mi) {
    int mt = mtbase + mi;
    ushort w0[4], w1[4];
#pragma unroll
    for (int r = 0; r < 4; ++r) {
      w0[r] = f2bfu(fmaxf(acc[mi][0][r] + cb0, 0.f));
      w1[r] = f2bfu(fmaxf(acc[mi][1][r] + cb1, 0.f));
    }
    uint2 pk0, pk1;
    __builtin_memcpy(&pk0, w0, 8);
    __builtin_memcpy(&pk1, w1, 8);
    *(uint2*)&scr[wb + col * 20 + quad * 4] = pk0;          // oc=col
    *(uint2*)&scr[wb + (col + 16) * 20 + quad * 4] = pk1;   // oc=col+16
    ushort u[8];
#pragma unroll
    for (int e = 0; e < 8; ++e) u[e] = scr[wb + (quad * 8 + e) * 20 + col];
    s8b a2;
    __builtin_memcpy(&a2, u, 16);
    f32x4 zero = {0.f, 0.f, 0.f, 0.f};
    f32x4 d2 = __builtin_amdgcn_mfma_f32_16x16x32_bf16(a2, pf, zero, 0, 0, 0);
    int4 m4 = *(const int4*)(mrow + mt * 16 + quad * 4);
    float k0 = m4.x ? 0.f : 1.f;
    float k1 = m4.y ? 0.f : 1.f;
    float k2 = m4.z ? 0.f : 1.f;
    float k3 = m4.w ? 0.f : 1.f;
    if (col < NH) {
      float* op = outbase + mt * 16 + quad * 4;
      float v0 = d2[0] * k0; op[0] = v0; psum += v0; psq += v0 * v0;
      float v1 = d2[1] * k1; op[1] = v1; psum += v1; psq += v1 * v1;
      float v2 = d2[2] * k2; op[2] = v2; psum += v2; psq += v2 * v2;
      float v3 = d2[3] * k3; op[3] = v3; psum += v3; psq += v3 * v3;
    }
    if (col == 0) pcnt += k0 + k1 + k2 + k3;
  }

  psum += __shfl_down(psum, 16, 64); psum += __shfl_down(psum, 32, 64);
  psq  += __shfl_down(psq, 16, 64);  psq  += __shfl_down(psq, 32, 64);
  pcnt += __shfl_down(pcnt, 16, 64); pcnt += __shfl_down(pcnt, 32, 64);
  if (lane < 16) {
    redp[(w * 16 + lane) * 2] = psum;
    redp[(w * 16 + lane) * 2 + 1] = psq;
    if (lane == 0) redc[w] = pcnt;
  }
  __syncthreads();
  if (tid < 17) {
    float v;
    if (tid < 8) {
      v = redp[tid * 2] + redp[(16 + tid) * 2] + redp[(32 + tid) * 2] + redp[(48 + tid) * 2];
    } else if (tid < 16) {
      int nh = tid - 8;
      v = redp[nh * 2 + 1] + redp[(16 + nh) * 2 + 1] + redp[(32 + nh) * 2 + 1] + redp[(48 + nh) * 2 + 1];
    } else {
      v = redc[0] + redc[1] + redc[2] + redc[3];
    }
    atomicAdd(&sums[tid], v);
  }
}

// ---------------------------------------------------------------------------
// K4: masked BN normalize in-place. 8 floats/thread for memory-level
// parallelism on the L3-hot out re-read.
__global__ __launch_bounds__(256) void k_bn(
    float* __restrict__ out, const float* __restrict__ sums,
    const int* __restrict__ mask, const float* __restrict__ gamma,
    const float* __restrict__ beta) {
  __shared__ float sc[NH], sh[NH];
  int tid = threadIdx.x;
  if (tid < NH) {
    float cnt = sums[16];
    float mean = sums[tid] / cnt;
    float var = sums[NH + tid] / cnt - mean * mean;
    float inv = rsqrtf(var + 1e-5f) * gamma[tid];
    sc[tid] = inv;
    sh[tid] = fmaf(-mean, inv, beta[tid]);
  }
  __syncthreads();
  size_t e = ((size_t)blockIdx.x * 256 + tid) * 8;  // 8 consecutive l
  int l = (int)(e & (LL - 1));
  int bn = (int)(e >> 17);
  int n = bn & 7;
  int b = bn >> 3;
  const int4 mv0 = *(const int4*)(mask + b * LL + l);
  const int4 mv1 = *(const int4*)(mask + b * LL + l + 4);
  float4 v0 = *(float4*)(out + e);
  float4 v1 = *(float4*)(out + e + 4);
  float s = sc[n], h = sh[n];
  v0.x = mv0.x ? v0.x : fmaf(v0.x, s, h);
  v0.y = mv0.y ? v0.y : fmaf(v0.y, s, h);
  v0.z = mv0.z ? v0.z : fmaf(v0.z, s, h);
  v0.w = mv0.w ? v0.w : fmaf(v0.w, s, h);
  v1.x = mv1.x ? v1.x : fmaf(v1.x, s, h);
  v1.y = mv1.y ? v1.y : fmaf(v1.y, s, h);
  v1.z = mv1.z ? v1.z : fmaf(v1.z, s, h);
  v1.w = mv1.w ? v1.w : fmaf(v1.w, s, h);
  *(float4*)(out + e) = v0;
  *(float4*)(out + e + 4) = v1;
}

// ---------------------------------------------------------------------------
extern "C" void kernel_launch(void* const* d_in, const int* in_sizes, int n_in,
                              void* d_out, int out_size, void* d_ws, size_t ws_size,
                              hipStream_t stream) {
  const float* prev   = (const float*)d_in[0];
  const int*   mask   = (const int*)d_in[1];
  const float* curr   = (const float*)d_in[3];
  const float* conv_w = (const float*)d_in[5];
  const float* conv_b = (const float*)d_in[6];
  const float* proj_w = (const float*)d_in[7];
  const float* g_w1   = (const float*)d_in[8];
  const float* g_b1   = (const float*)d_in[9];
  const float* g_w2   = (const float*)d_in[10];
  const float* g_b2   = (const float*)d_in[11];
  const float* bn_g   = (const float*)d_in[12];
  const float* bn_b   = (const float*)d_in[13];
  float* out = (float*)d_out;

  char* ws = (char*)d_ws;
  ushort* bfrag  = (ushort*)(ws);                    // 26624 B
  ushort* pwf    = (ushort*)(ws + 26624);            // 1024 B
  ushort* bfragG = (ushort*)(ws + 27648);            // 5120 B
  float*  sums   = (float*)(ws + 32768);             // 68 B
  float*  gate2  = (float*)(ws + 36864);             // 131072 B  [b][c][t]
  ushort* cum    = (ushort*)(ws + 36864 + 131072);   // 33554432 B [b][c][t][l]

  k_gen<<<64, 256, 0, stream>>>(conv_w, proj_w, g_w1, bfrag, pwf, bfragG, sums);
  k_gate<<<BB * TT, 256, 0, stream>>>(prev, curr, bfragG, g_b1, g_w2, g_b2, gate2);
  k_cum<<<(BB * CC * LL) / 256, 256, 0, stream>>>(prev, curr, gate2, cum);
  k_cov<<<BB * TT, 256, 0, stream>>>(cum, bfrag, pwf, conv_b, mask, out, sums);
  k_bn<<<(BB * NH * TT * LL) / (256 * 8), 256, 0, stream>>>(out, sums, mask, bn_g, bn_b);
}